// Round 3
// baseline (207.579 us; speedup 1.0000x reference)
//
#include <hip/hip_runtime.h>

// GPSA bf16-MFMA v3. B=64, N=300, C=256, H=8, hd=32.
// K0 prep: convert x/Wqk/Wv/Wproj -> bf16; gpos[h,i,j] = bf16(g_h * softmax_j(...)) [8,304,304]
// K2 gemm_qkv_mfma: x_bf @ W^T -> q(pre-scaled by 1/sqrt(32)),k,v bf16 [B,H,300,32]
// K3 attn_mfma: S^T = mfma(K,Q) puts P in A-operand layout -> PV straight from regs
//               (zero-padded k-slots), no LDS transpose. o bf16 [B,300,256]
// K4 gemm_proj_mfma: o_bf @ Wproj^T + bias -> fp32 out

#define NSEQ 300
#define HEADS 8
#define HD 32

typedef short v8s __attribute__((ext_vector_type(8)));
typedef float v4f __attribute__((ext_vector_type(4)));
typedef unsigned int v4u __attribute__((ext_vector_type(4)));

__device__ __forceinline__ ushort f2bf(float f) {
    unsigned u = __float_as_uint(f);
    u = (u + 0x7FFFu + ((u >> 16) & 1u)) >> 16;   // RNE
    return (ushort)u;
}

// pack two fp32 -> packed bf16x2 (lo=a, hi=b) in 5 VALU via v_perm
__device__ __forceinline__ unsigned pk2bf(float a, float b) {
    unsigned ua = __float_as_uint(a), ub = __float_as_uint(b);
    ua += 0x7FFFu + ((ua >> 16) & 1u);
    ub += 0x7FFFu + ((ub >> 16) & 1u);
    return __builtin_amdgcn_perm(ub, ua, 0x07060302);  // [ua.hi16 | ub.hi16]
}

// ---------------- K0: prep = convert + gated positional softmax ----------------
// blocks 0..5055: fp32->bf16 convert (float4 units: x 1228800 | Wqk 32768 | Wv 16384 | Wproj 16384)
// blocks 5056..5663: gpos rows (608 blocks x 4 rows, 64 lanes each)
__global__ __launch_bounds__(256) void prep_kernel(
    const float* __restrict__ x, const float* __restrict__ Wqk,
    const float* __restrict__ Wv, const float* __restrict__ Wproj,
    const float* __restrict__ Wpos, const float* __restrict__ bpos,
    const float* __restrict__ gating,
    ushort* __restrict__ x_bf, ushort* __restrict__ wqkv_bf,
    ushort* __restrict__ wproj_bf, ushort* __restrict__ gpos)
{
    const int NX = 1228800, NQK = 32768, NV = 16384;
    int bid = blockIdx.x;
    if (bid < 5056) {
        int idx = bid * 256 + threadIdx.x;
        const float* src; ushort* dst;
        if (idx < NX)                { src = x + (size_t)idx * 4;              dst = x_bf + (size_t)idx * 4; }
        else if (idx < NX + NQK)     { int t = idx - NX;           src = Wqk + (size_t)t * 4;   dst = wqkv_bf + (size_t)t * 4; }
        else if (idx < NX + NQK + NV){ int t = idx - NX - NQK;     src = Wv + (size_t)t * 4;    dst = wqkv_bf + 131072 + (size_t)t * 4; }
        else                         { int t = idx - NX - NQK - NV; src = Wproj + (size_t)t * 4; dst = wproj_bf + (size_t)t * 4; }
        float4 v = *(const float4*)src;
        ushort4 o; o.x = f2bf(v.x); o.y = f2bf(v.y); o.z = f2bf(v.z); o.w = f2bf(v.w);
        *(ushort4*)dst = o;
        return;
    }
    int sub = bid - 5056;                       // 0..607
    int h = sub / 76;
    int i = (sub % 76) * 4 + (threadIdx.x >> 6);  // row 0..303
    int lane = threadIdx.x & 63;
    ushort* gr = gpos + ((size_t)h * 304 + i) * 304;
    if (i >= NSEQ) {                            // zero pad rows
#pragma unroll
        for (int t = 0; t < 5; ++t) {
            int j = lane + 64 * t;
            if (j < 304) gr[j] = 0;
        }
        return;
    }
    float w0 = Wpos[h * 3 + 0], w2 = Wpos[h * 3 + 2], bb = bpos[h];
    float g = 1.f / (1.f + __expf(-gating[h]));
    float sv[5]; float m = -1e30f;
#pragma unroll
    for (int t = 0; t < 5; ++t) {
        int j = lane + 64 * t;
        float d = (float)(j - i);
        float lg = fmaf(w2, d * d, fmaf(w0, d, bb));
        sv[t] = (j < NSEQ) ? lg : -1e30f;       // logits +-7000: max-sub required
        m = fmaxf(m, sv[t]);
    }
#pragma unroll
    for (int off = 32; off > 0; off >>= 1) m = fmaxf(m, __shfl_xor(m, off));
    float sum = 0.f;
#pragma unroll
    for (int t = 0; t < 5; ++t) { sv[t] = __expf(sv[t] - m); sum += sv[t]; }
#pragma unroll
    for (int off = 32; off > 0; off >>= 1) sum += __shfl_xor(sum, off);
    float gi = g / sum;
#pragma unroll
    for (int t = 0; t < 5; ++t) {
        int j = lane + 64 * t;
        if (j < NSEQ) gr[j] = f2bf(sv[t] * gi);
        else if (j < 304) gr[j] = 0;            // zero pad cols
    }
}

// ---------------- K2: QKV GEMM, bf16 MFMA ----------------
// C[m,col] = sum_k x[m,k]*W[col,k]; 128x128 tile, BK=64, 4 waves (2x2 of 64x64).
// q output pre-scaled by 1/sqrt(32).
__global__ __launch_bounds__(256) void gemm_qkv_mfma(
    const ushort* __restrict__ A, const ushort* __restrict__ Bw,
    ushort* __restrict__ qo, ushort* __restrict__ ko, ushort* __restrict__ vo)
{
    __shared__ ushort As[128 * 72];   // stride 72 (144B): 16B-mult, dword%32=4 -> 2-way (free)
    __shared__ ushort Bs[128 * 72];
    int tid = threadIdx.x;
    int wave = tid >> 6, lane = tid & 63, li = lane & 15, qd = lane >> 4;
    int row0 = blockIdx.y * 128, col0 = blockIdx.x * 128;
    int rh = wave >> 1, ch = wave & 1;

    v4f acc[4][4];
#pragma unroll
    for (int i = 0; i < 4; ++i)
#pragma unroll
        for (int j = 0; j < 4; ++j) acc[i][j] = (v4f){0.f, 0.f, 0.f, 0.f};

    for (int k0 = 0; k0 < 256; k0 += 64) {
#pragma unroll
        for (int s = 0; s < 4; ++s) {
            int c = s * 256 + tid;
            int r = c >> 3, k8 = (c & 7) * 8;
            *(uint4*)&As[r * 72 + k8] = *(const uint4*)(A + (size_t)(row0 + r) * 256 + k0 + k8);
            *(uint4*)&Bs[r * 72 + k8] = *(const uint4*)(Bw + (size_t)(col0 + r) * 256 + k0 + k8);
        }
        __syncthreads();
#pragma unroll
        for (int kc = 0; kc < 64; kc += 32) {
            v8s a[4], b[4];
#pragma unroll
            for (int mt = 0; mt < 4; ++mt)
                a[mt] = *(const v8s*)&As[(rh * 64 + mt * 16 + li) * 72 + kc + qd * 8];
#pragma unroll
            for (int nt = 0; nt < 4; ++nt)
                b[nt] = *(const v8s*)&Bs[(ch * 64 + nt * 16 + li) * 72 + kc + qd * 8];
#pragma unroll
            for (int mt = 0; mt < 4; ++mt)
#pragma unroll
                for (int nt = 0; nt < 4; ++nt)
                    acc[mt][nt] = __builtin_amdgcn_mfma_f32_16x16x32_bf16(a[mt], b[nt], acc[mt][nt], 0, 0, 0);
        }
        __syncthreads();
    }

    int reg3 = blockIdx.x >> 1;  // 0=q 1=k 2=v
    ushort* ob = (reg3 == 0) ? qo : (reg3 == 1) ? ko : vo;
    float sc = (reg3 == 0) ? 0.17677669529663687f : 1.0f;  // fold 1/sqrt(hd) into q
    int cb = (blockIdx.x & 1) * 128 + ch * 64;
#pragma unroll
    for (int mt = 0; mt < 4; ++mt)
#pragma unroll
        for (int nt = 0; nt < 4; ++nt) {
            int col = cb + nt * 16 + li;
            int hh = col >> 5, dd = col & 31;
#pragma unroll
            for (int r = 0; r < 4; ++r) {
                unsigned row = row0 + rh * 64 + mt * 16 + qd * 4 + r;
                unsigned bb = row / 300u;
                unsigned nn = row - bb * 300u;
                ob[(((size_t)bb * 8 + hh) * 300 + nn) * 32 + dd] = f2bf(acc[mt][nt][r] * sc);
            }
        }
}

// ---------------- K3: fused attention, register-resident P ----------------
// S^T = mfma(A=K_tile, B=Q_tile): lane li = query row i, regs (qd*4+r) = key col j.
// P[i][j] built in regs, packed bf16, fed as A-operand (k-slots 4..7 zero) to PV.
__global__ __launch_bounds__(256, 2) void attn_mfma(
    const ushort* __restrict__ qg, const ushort* __restrict__ kg,
    const ushort* __restrict__ vg, const ushort* __restrict__ gpos,
    const float* __restrict__ gating, ushort* __restrict__ og)
{
    __shared__ ushort Ks[304 * 40];    // [seq][k] stride 40 (80B)
    __shared__ ushort Vt[32 * 328];    // [dim][seq] stride 328 (656B), seq 300..327 zero

    int bh = blockIdx.x, b = bh >> 3, h = bh & 7;
    int tid = threadIdx.x, wave = tid >> 6, lane = tid & 63, li = lane & 15, qd = lane >> 4;
    const ushort* kb = kg + (size_t)bh * 9600;
    const ushort* vb = vg + (size_t)bh * 9600;

    for (int c = tid; c < 1200; c += 256) {        // K: 300 rows x 4 u8-chunks
        int r = c >> 2, k8 = (c & 3) * 8;
        *(uint4*)&Ks[r * 40 + k8] = *(const uint4*)(kb + r * 32 + k8);
    }
    for (int c = tid; c < 2400; c += 256) {        // V transpose: 300 x 8 u4-chunks
        int sq = c >> 3, d4 = (c & 7) * 4;
        ushort4 t = *(const ushort4*)(vb + sq * 32 + d4);
        Vt[(d4 + 0) * 328 + sq] = t.x;
        Vt[(d4 + 1) * 328 + sq] = t.y;
        Vt[(d4 + 2) * 328 + sq] = t.z;
        Vt[(d4 + 3) * 328 + sq] = t.w;
    }
    for (int c = tid; c < 896; c += 256) {         // Vt seq pad 300..327 -> 0
        int d = c & 31, s = c >> 5;
        Vt[d * 328 + 300 + s] = 0;
    }
    float g = 1.f / (1.f + __expf(-gating[h]));
    float omg = 1.f - g;
    __syncthreads();

    for (int rg = wave; rg < 19; rg += 4) {
        int i0 = rg * 16;
        // Q as B-operand: lane li holds Q row (i0+li), k=qd*8.. (rows>=300 read into
        // adjacent k_bf region: valid memory, finite values, masked at store)
        v8s bq = *(const v8s*)(qg + (size_t)bh * 9600 + (i0 + li) * 32 + qd * 8);

        // ---- S^T tiles: e[nt][r] = exp(q_i . k_j), i = i0+li, j = nt*16+qd*4+r ----
        float e[19][4];
        float esum = 0.f;
#pragma unroll
        for (int nt = 0; nt < 19; ++nt) {
            v8s ak = *(const v8s*)&Ks[(nt * 16 + li) * 40 + qd * 8];
            v4f s = __builtin_amdgcn_mfma_f32_16x16x32_bf16(ak, bq, (v4f){0.f, 0.f, 0.f, 0.f}, 0, 0, 0);
#pragma unroll
            for (int r = 0; r < 4; ++r) {
                float ev = __expf(s[r]);           // scale folded into q
                if (nt == 18) ev = (qd < 3) ? ev : 0.f;   // j >= 300 (Ks rows 300..303 stale)
                e[nt][r] = ev;
                esum += ev;
            }
        }
        esum += __shfl_xor(esum, 16);
        esum += __shfl_xor(esum, 32);              // row sum for i = i0+li
        float ps = omg / esum;                     // (skip /attn.sum: it's 1 +- 1e-6)

        const ushort* gp = gpos + ((size_t)h * 304 + (i0 + li)) * 304;
        v4f O0 = {0.f, 0.f, 0.f, 0.f}, O1 = {0.f, 0.f, 0.f, 0.f};
#pragma unroll
        for (int nt = 0; nt < 19; ++nt) {
            uint2 gpl = *(const uint2*)(gp + nt * 16 + qd * 4);   // 4 bf16 gpos, contiguous
            float g0 = __uint_as_float(gpl.x << 16);
            float g1 = __uint_as_float(gpl.x & 0xFFFF0000u);
            float g2 = __uint_as_float(gpl.y << 16);
            float g3 = __uint_as_float(gpl.y & 0xFFFF0000u);
            unsigned pk0 = pk2bf(fmaf(ps, e[nt][0], g0), fmaf(ps, e[nt][1], g1));
            unsigned pk1 = pk2bf(fmaf(ps, e[nt][2], g2), fmaf(ps, e[nt][3], g3));
            v8s a2 = __builtin_bit_cast(v8s, (v4u){pk0, pk1, 0u, 0u});
            uint2 v0 = *(const uint2*)&Vt[li * 328 + nt * 16 + qd * 4];
            uint2 v1 = *(const uint2*)&Vt[(16 + li) * 328 + nt * 16 + qd * 4];
            v8s b0 = __builtin_bit_cast(v8s, (v4u){v0.x, v0.y, 0u, 0u});
            v8s b1 = __builtin_bit_cast(v8s, (v4u){v1.x, v1.y, 0u, 0u});
            O0 = __builtin_amdgcn_mfma_f32_16x16x32_bf16(a2, b0, O0, 0, 0, 0);
            O1 = __builtin_amdgcn_mfma_f32_16x16x32_bf16(a2, b1, O1, 0, 0, 0);
        }
#pragma unroll
        for (int r = 0; r < 4; ++r) {
            int row = i0 + qd * 4 + r;
            if (row < NSEQ) {
                size_t base = ((size_t)b * NSEQ + row) * 256 + h * 32 + li;
                og[base] = f2bf(O0[r]);
                og[base + 16] = f2bf(O1[r]);
            }
        }
    }
}

// ---------------- K4: output projection, bf16 MFMA + fp32 bias ----------------
__global__ __launch_bounds__(256) void gemm_proj_mfma(
    const ushort* __restrict__ A, const ushort* __restrict__ Bw,
    const float* __restrict__ bias, float* __restrict__ out)
{
    __shared__ ushort As[128 * 72];
    __shared__ ushort Bs[128 * 72];
    int tid = threadIdx.x;
    int wave = tid >> 6, lane = tid & 63, li = lane & 15, qd = lane >> 4;
    int row0 = blockIdx.y * 128, col0 = blockIdx.x * 128;
    int rh = wave >> 1, ch = wave & 1;

    v4f acc[4][4];
#pragma unroll
    for (int i = 0; i < 4; ++i)
#pragma unroll
        for (int j = 0; j < 4; ++j) acc[i][j] = (v4f){0.f, 0.f, 0.f, 0.f};

    for (int k0 = 0; k0 < 256; k0 += 64) {
#pragma unroll
        for (int s = 0; s < 4; ++s) {
            int c = s * 256 + tid;
            int r = c >> 3, k8 = (c & 7) * 8;
            *(uint4*)&As[r * 72 + k8] = *(const uint4*)(A + (size_t)(row0 + r) * 256 + k0 + k8);
            *(uint4*)&Bs[r * 72 + k8] = *(const uint4*)(Bw + (size_t)(col0 + r) * 256 + k0 + k8);
        }
        __syncthreads();
#pragma unroll
        for (int kc = 0; kc < 64; kc += 32) {
            v8s a[4], b[4];
#pragma unroll
            for (int mt = 0; mt < 4; ++mt)
                a[mt] = *(const v8s*)&As[(rh * 64 + mt * 16 + li) * 72 + kc + qd * 8];
#pragma unroll
            for (int nt = 0; nt < 4; ++nt)
                b[nt] = *(const v8s*)&Bs[(ch * 64 + nt * 16 + li) * 72 + kc + qd * 8];
#pragma unroll
            for (int mt = 0; mt < 4; ++mt)
#pragma unroll
                for (int nt = 0; nt < 4; ++nt)
                    acc[mt][nt] = __builtin_amdgcn_mfma_f32_16x16x32_bf16(a[mt], b[nt], acc[mt][nt], 0, 0, 0);
        }
        __syncthreads();
    }

#pragma unroll
    for (int mt = 0; mt < 4; ++mt)
#pragma unroll
        for (int nt = 0; nt < 4; ++nt) {
            int col = col0 + ch * 64 + nt * 16 + li;
            float bv = bias[col];
#pragma unroll
            for (int r = 0; r < 4; ++r) {
                int row = row0 + rh * 64 + mt * 16 + qd * 4 + r;
                out[(size_t)row * 256 + col] = acc[mt][nt][r] + bv;
            }
        }
}

extern "C" void kernel_launch(void* const* d_in, const int* in_sizes, int n_in,
                              void* d_out, int out_size, void* d_ws, size_t ws_size,
                              hipStream_t stream) {
    const float* x      = (const float*)d_in[0];
    const float* Wqk    = (const float*)d_in[1];
    const float* Wv     = (const float*)d_in[2];
    const float* Wpos   = (const float*)d_in[3];
    const float* bpos   = (const float*)d_in[4];
    const float* Wproj  = (const float*)d_in[5];
    const float* bproj  = (const float*)d_in[6];
    const float* gating = (const float*)d_in[7];
    float* out = (float*)d_out;

    ushort* gpos     = (ushort*)d_ws;             // 8*304*304 = 739,328
    ushort* x_bf     = gpos + 739328;             // 4,915,200
    ushort* wqkv_bf  = x_bf + 4915200;            // 196,608 (Wqk 0..511, Wv 512..767)
    ushort* wproj_bf = wqkv_bf + 196608;          // 65,536
    ushort* q_bf     = wproj_bf + 65536;          // 4,915,200 each
    ushort* k_bf     = q_bf + 4915200;
    ushort* v_bf     = k_bf + 4915200;
    ushort* o_bf     = v_bf + 4915200;

    prep_kernel<<<5664, 256, 0, stream>>>(x, Wqk, Wv, Wproj, Wpos, bpos, gating,
                                          x_bf, wqkv_bf, wproj_bf, gpos);
    gemm_qkv_mfma<<<dim3(6, 150), 256, 0, stream>>>(x_bf, wqkv_bf, q_bf, k_bf, v_bf);
    attn_mfma<<<dim3(64 * HEADS), 256, 0, stream>>>(q_bf, k_bf, v_bf, gpos, gating, o_bf);
    gemm_proj_mfma<<<dim3(2, 150), 256, 0, stream>>>(o_bf, wproj_bf, bproj, out);
}

// Round 4
// 206.351 us; speedup vs baseline: 1.0060x; 1.0060x over previous
//
#include <hip/hip_runtime.h>

// GPSA bf16-MFMA v4. B=64, N=300, C=256, H=8, hd=32.
// K0 prep: convert x/Wqk/Wv/Wproj -> bf16; gpos[h,i,j] = bf16(g_h * softmax_j(...)) [8,304,304]
// K2 gemm_qkv_mfma: x_bf @ W^T -> q(pre-scaled by 1/sqrt(32)),k,v bf16 [B,H,300,32]
// K3 attn_mfma: S^T = mfma(K,Q) -> P in A-operand layout, e kept PACKED bf16 in regs
//               (38 VGPRs, no spill — r3's fp32 e[19][4] spilled: 57MB scratch writes),
//               gpos prefetched to regs during S-pass. PV from regs, half-K MFMAs.
// K4 gemm_proj_mfma: o_bf @ Wproj^T + bias -> fp32 out

#define NSEQ 300
#define HEADS 8
#define HD 32

typedef short v8s __attribute__((ext_vector_type(8)));
typedef float v4f __attribute__((ext_vector_type(4)));
typedef unsigned int v4u __attribute__((ext_vector_type(4)));

__device__ __forceinline__ ushort f2bf(float f) {
    unsigned u = __float_as_uint(f);
    u = (u + 0x7FFFu + ((u >> 16) & 1u)) >> 16;   // RNE
    return (ushort)u;
}

// pack two fp32 -> packed bf16x2 (lo=a, hi=b) via v_perm
__device__ __forceinline__ unsigned pk2bf(float a, float b) {
    unsigned ua = __float_as_uint(a), ub = __float_as_uint(b);
    ua += 0x7FFFu + ((ua >> 16) & 1u);
    ub += 0x7FFFu + ((ub >> 16) & 1u);
    return __builtin_amdgcn_perm(ub, ua, 0x07060302);  // [ua.hi16 | ub.hi16]
}

// ---------------- K0: prep = convert + gated positional softmax ----------------
__global__ __launch_bounds__(256) void prep_kernel(
    const float* __restrict__ x, const float* __restrict__ Wqk,
    const float* __restrict__ Wv, const float* __restrict__ Wproj,
    const float* __restrict__ Wpos, const float* __restrict__ bpos,
    const float* __restrict__ gating,
    ushort* __restrict__ x_bf, ushort* __restrict__ wqkv_bf,
    ushort* __restrict__ wproj_bf, ushort* __restrict__ gpos)
{
    const int NX = 1228800, NQK = 32768, NV = 16384;
    int bid = blockIdx.x;
    if (bid < 5056) {
        int idx = bid * 256 + threadIdx.x;
        const float* src; ushort* dst;
        if (idx < NX)                { src = x + (size_t)idx * 4;              dst = x_bf + (size_t)idx * 4; }
        else if (idx < NX + NQK)     { int t = idx - NX;           src = Wqk + (size_t)t * 4;   dst = wqkv_bf + (size_t)t * 4; }
        else if (idx < NX + NQK + NV){ int t = idx - NX - NQK;     src = Wv + (size_t)t * 4;    dst = wqkv_bf + 131072 + (size_t)t * 4; }
        else                         { int t = idx - NX - NQK - NV; src = Wproj + (size_t)t * 4; dst = wproj_bf + (size_t)t * 4; }
        float4 v = *(const float4*)src;
        ushort4 o; o.x = f2bf(v.x); o.y = f2bf(v.y); o.z = f2bf(v.z); o.w = f2bf(v.w);
        *(ushort4*)dst = o;
        return;
    }
    int sub = bid - 5056;                       // 0..607
    int h = sub / 76;
    int i = (sub % 76) * 4 + (threadIdx.x >> 6);  // row 0..303
    int lane = threadIdx.x & 63;
    ushort* gr = gpos + ((size_t)h * 304 + i) * 304;
    if (i >= NSEQ) {
#pragma unroll
        for (int t = 0; t < 5; ++t) {
            int j = lane + 64 * t;
            if (j < 304) gr[j] = 0;
        }
        return;
    }
    float w0 = Wpos[h * 3 + 0], w2 = Wpos[h * 3 + 2], bb = bpos[h];
    float g = 1.f / (1.f + __expf(-gating[h]));
    float sv[5]; float m = -1e30f;
#pragma unroll
    for (int t = 0; t < 5; ++t) {
        int j = lane + 64 * t;
        float d = (float)(j - i);
        float lg = fmaf(w2, d * d, fmaf(w0, d, bb));
        sv[t] = (j < NSEQ) ? lg : -1e30f;       // logits +-7000: max-sub required
        m = fmaxf(m, sv[t]);
    }
#pragma unroll
    for (int off = 32; off > 0; off >>= 1) m = fmaxf(m, __shfl_xor(m, off));
    float sum = 0.f;
#pragma unroll
    for (int t = 0; t < 5; ++t) { sv[t] = __expf(sv[t] - m); sum += sv[t]; }
#pragma unroll
    for (int off = 32; off > 0; off >>= 1) sum += __shfl_xor(sum, off);
    float gi = g / sum;
#pragma unroll
    for (int t = 0; t < 5; ++t) {
        int j = lane + 64 * t;
        if (j < NSEQ) gr[j] = f2bf(sv[t] * gi);
        else if (j < 304) gr[j] = 0;
    }
}

// ---------------- K2: QKV GEMM, bf16 MFMA ----------------
__global__ __launch_bounds__(256) void gemm_qkv_mfma(
    const ushort* __restrict__ A, const ushort* __restrict__ Bw,
    ushort* __restrict__ qo, ushort* __restrict__ ko, ushort* __restrict__ vo)
{
    __shared__ ushort As[128 * 72];   // stride 72 (144B): 16B-mult, dword%32=4 -> 2-way (free)
    __shared__ ushort Bs[128 * 72];
    int tid = threadIdx.x;
    int wave = tid >> 6, lane = tid & 63, li = lane & 15, qd = lane >> 4;
    int row0 = blockIdx.y * 128, col0 = blockIdx.x * 128;
    int rh = wave >> 1, ch = wave & 1;

    v4f acc[4][4];
#pragma unroll
    for (int i = 0; i < 4; ++i)
#pragma unroll
        for (int j = 0; j < 4; ++j) acc[i][j] = (v4f){0.f, 0.f, 0.f, 0.f};

    for (int k0 = 0; k0 < 256; k0 += 64) {
#pragma unroll
        for (int s = 0; s < 4; ++s) {
            int c = s * 256 + tid;
            int r = c >> 3, k8 = (c & 7) * 8;
            *(uint4*)&As[r * 72 + k8] = *(const uint4*)(A + (size_t)(row0 + r) * 256 + k0 + k8);
            *(uint4*)&Bs[r * 72 + k8] = *(const uint4*)(Bw + (size_t)(col0 + r) * 256 + k0 + k8);
        }
        __syncthreads();
#pragma unroll
        for (int kc = 0; kc < 64; kc += 32) {
            v8s a[4], b[4];
#pragma unroll
            for (int mt = 0; mt < 4; ++mt)
                a[mt] = *(const v8s*)&As[(rh * 64 + mt * 16 + li) * 72 + kc + qd * 8];
#pragma unroll
            for (int nt = 0; nt < 4; ++nt)
                b[nt] = *(const v8s*)&Bs[(ch * 64 + nt * 16 + li) * 72 + kc + qd * 8];
#pragma unroll
            for (int mt = 0; mt < 4; ++mt)
#pragma unroll
                for (int nt = 0; nt < 4; ++nt)
                    acc[mt][nt] = __builtin_amdgcn_mfma_f32_16x16x32_bf16(a[mt], b[nt], acc[mt][nt], 0, 0, 0);
        }
        __syncthreads();
    }

    int reg3 = blockIdx.x >> 1;  // 0=q 1=k 2=v
    ushort* ob = (reg3 == 0) ? qo : (reg3 == 1) ? ko : vo;
    float sc = (reg3 == 0) ? 0.17677669529663687f : 1.0f;  // fold 1/sqrt(hd) into q
    int cb = (blockIdx.x & 1) * 128 + ch * 64;
#pragma unroll
    for (int mt = 0; mt < 4; ++mt)
#pragma unroll
        for (int nt = 0; nt < 4; ++nt) {
            int col = cb + nt * 16 + li;
            int hh = col >> 5, dd = col & 31;
#pragma unroll
            for (int r = 0; r < 4; ++r) {
                unsigned row = row0 + rh * 64 + mt * 16 + qd * 4 + r;
                unsigned bb = row / 300u;
                unsigned nn = row - bb * 300u;
                ob[(((size_t)bb * 8 + hh) * 300 + nn) * 32 + dd] = f2bf(acc[mt][nt][r] * sc);
            }
        }
}

// ---------------- K3: fused attention, register-resident packed P ----------------
// S^T = mfma(A=K_tile, B=Q_tile): lane li = query row i, regs (qd*4+r) = key col j.
// e kept packed bf16 (epk[19][2] = 38 VGPRs); gpos prefetched during S-pass.
__global__ __launch_bounds__(256, 2) void attn_mfma(
    const ushort* __restrict__ qg, const ushort* __restrict__ kg,
    const ushort* __restrict__ vg, const ushort* __restrict__ gpos,
    const float* __restrict__ gating, ushort* __restrict__ og)
{
    __shared__ ushort Ks[304 * 40];    // [seq][k] stride 40 (80B)
    __shared__ ushort Vt[32 * 328];    // [dim][seq] stride 328 (656B), seq 300..327 zero

    int bh = blockIdx.x, b = bh >> 3, h = bh & 7;
    int tid = threadIdx.x, wave = tid >> 6, lane = tid & 63, li = lane & 15, qd = lane >> 4;
    const ushort* kb = kg + (size_t)bh * 9600;
    const ushort* vb = vg + (size_t)bh * 9600;

    for (int c = tid; c < 1200; c += 256) {        // K: 300 rows x 4 u8-chunks
        int r = c >> 2, k8 = (c & 3) * 8;
        *(uint4*)&Ks[r * 40 + k8] = *(const uint4*)(kb + r * 32 + k8);
    }
    for (int c = tid; c < 2400; c += 256) {        // V transpose: 300 x 8 u4-chunks
        int sq = c >> 3, d4 = (c & 7) * 4;
        ushort4 t = *(const ushort4*)(vb + sq * 32 + d4);
        Vt[(d4 + 0) * 328 + sq] = t.x;
        Vt[(d4 + 1) * 328 + sq] = t.y;
        Vt[(d4 + 2) * 328 + sq] = t.z;
        Vt[(d4 + 3) * 328 + sq] = t.w;
    }
    for (int c = tid; c < 896; c += 256) {         // Vt seq pad 300..327 -> 0
        int d = c & 31, s = c >> 5;
        Vt[d * 328 + 300 + s] = 0;
    }
    float g = 1.f / (1.f + __expf(-gating[h]));
    float omg = 1.f - g;
    __syncthreads();

    for (int rg = wave; rg < 19; rg += 4) {
        int i0 = rg * 16;
        // Q as B-operand: lane li holds Q row (i0+li); rows>=300 read into adjacent
        // k_bf region (valid memory, finite, masked at store)
        v8s bq = *(const v8s*)(qg + (size_t)bh * 9600 + (i0 + li) * 32 + qd * 8);
        const ushort* gp = gpos + ((size_t)h * 304 + (i0 + li)) * 304;

        // ---- S^T pass: e packed bf16 in regs; gpos prefetched ----
        unsigned epk[19][2];
        uint2 gpl[19];
        float esum = 0.f;
#pragma unroll
        for (int nt = 0; nt < 19; ++nt) {
            gpl[nt] = *(const uint2*)(gp + nt * 16 + qd * 4);   // prefetch (consumed in PV pass)
            v8s ak = *(const v8s*)&Ks[(nt * 16 + li) * 40 + qd * 8];
            v4f s = __builtin_amdgcn_mfma_f32_16x16x32_bf16(ak, bq, (v4f){0.f, 0.f, 0.f, 0.f}, 0, 0, 0);
            float e0 = __expf(s[0]);               // scale folded into q
            float e1 = __expf(s[1]);
            float e2 = __expf(s[2]);
            float e3 = __expf(s[3]);
            if (nt == 18 && qd == 3) { e0 = e1 = e2 = e3 = 0.f; }  // j >= 300
            esum += (e0 + e1) + (e2 + e3);
            epk[nt][0] = pk2bf(e0, e1);
            epk[nt][1] = pk2bf(e2, e3);
        }
        esum += __shfl_xor(esum, 16);
        esum += __shfl_xor(esum, 32);              // row sum for i = i0+li
        float ps = omg / esum;                     // (skip /attn.sum: it's 1 +- 1e-6)

        // ---- PV pass: P = ps*e + gpos, packed, fed as A-operand (k-slots 4..7 = 0) ----
        v4f O0 = {0.f, 0.f, 0.f, 0.f}, O1 = {0.f, 0.f, 0.f, 0.f};
#pragma unroll
        for (int nt = 0; nt < 19; ++nt) {
            float e0 = __uint_as_float(epk[nt][0] << 16);
            float e1 = __uint_as_float(epk[nt][0] & 0xFFFF0000u);
            float e2 = __uint_as_float(epk[nt][1] << 16);
            float e3 = __uint_as_float(epk[nt][1] & 0xFFFF0000u);
            float g0 = __uint_as_float(gpl[nt].x << 16);
            float g1 = __uint_as_float(gpl[nt].x & 0xFFFF0000u);
            float g2 = __uint_as_float(gpl[nt].y << 16);
            float g3 = __uint_as_float(gpl[nt].y & 0xFFFF0000u);
            unsigned pk0 = pk2bf(fmaf(ps, e0, g0), fmaf(ps, e1, g1));
            unsigned pk1 = pk2bf(fmaf(ps, e2, g2), fmaf(ps, e3, g3));
            v8s a2 = __builtin_bit_cast(v8s, (v4u){pk0, pk1, 0u, 0u});
            uint2 v0 = *(const uint2*)&Vt[li * 328 + nt * 16 + qd * 4];
            uint2 v1 = *(const uint2*)&Vt[(16 + li) * 328 + nt * 16 + qd * 4];
            v8s b0 = __builtin_bit_cast(v8s, (v4u){v0.x, v0.y, 0u, 0u});
            v8s b1 = __builtin_bit_cast(v8s, (v4u){v1.x, v1.y, 0u, 0u});
            O0 = __builtin_amdgcn_mfma_f32_16x16x32_bf16(a2, b0, O0, 0, 0, 0);
            O1 = __builtin_amdgcn_mfma_f32_16x16x32_bf16(a2, b1, O1, 0, 0, 0);
        }
#pragma unroll
        for (int r = 0; r < 4; ++r) {
            int row = i0 + qd * 4 + r;
            if (row < NSEQ) {
                size_t base = ((size_t)b * NSEQ + row) * 256 + h * 32 + li;
                og[base] = f2bf(O0[r]);
                og[base + 16] = f2bf(O1[r]);
            }
        }
    }
}

// ---------------- K4: output projection, bf16 MFMA + fp32 bias ----------------
__global__ __launch_bounds__(256) void gemm_proj_mfma(
    const ushort* __restrict__ A, const ushort* __restrict__ Bw,
    const float* __restrict__ bias, float* __restrict__ out)
{
    __shared__ ushort As[128 * 72];
    __shared__ ushort Bs[128 * 72];
    int tid = threadIdx.x;
    int wave = tid >> 6, lane = tid & 63, li = lane & 15, qd = lane >> 4;
    int row0 = blockIdx.y * 128, col0 = blockIdx.x * 128;
    int rh = wave >> 1, ch = wave & 1;

    v4f acc[4][4];
#pragma unroll
    for (int i = 0; i < 4; ++i)
#pragma unroll
        for (int j = 0; j < 4; ++j) acc[i][j] = (v4f){0.f, 0.f, 0.f, 0.f};

    for (int k0 = 0; k0 < 256; k0 += 64) {
#pragma unroll
        for (int s = 0; s < 4; ++s) {
            int c = s * 256 + tid;
            int r = c >> 3, k8 = (c & 7) * 8;
            *(uint4*)&As[r * 72 + k8] = *(const uint4*)(A + (size_t)(row0 + r) * 256 + k0 + k8);
            *(uint4*)&Bs[r * 72 + k8] = *(const uint4*)(Bw + (size_t)(col0 + r) * 256 + k0 + k8);
        }
        __syncthreads();
#pragma unroll
        for (int kc = 0; kc < 64; kc += 32) {
            v8s a[4], b[4];
#pragma unroll
            for (int mt = 0; mt < 4; ++mt)
                a[mt] = *(const v8s*)&As[(rh * 64 + mt * 16 + li) * 72 + kc + qd * 8];
#pragma unroll
            for (int nt = 0; nt < 4; ++nt)
                b[nt] = *(const v8s*)&Bs[(ch * 64 + nt * 16 + li) * 72 + kc + qd * 8];
#pragma unroll
            for (int mt = 0; mt < 4; ++mt)
#pragma unroll
                for (int nt = 0; nt < 4; ++nt)
                    acc[mt][nt] = __builtin_amdgcn_mfma_f32_16x16x32_bf16(a[mt], b[nt], acc[mt][nt], 0, 0, 0);
        }
        __syncthreads();
    }

#pragma unroll
    for (int mt = 0; mt < 4; ++mt)
#pragma unroll
        for (int nt = 0; nt < 4; ++nt) {
            int col = col0 + ch * 64 + nt * 16 + li;
            float bv = bias[col];
#pragma unroll
            for (int r = 0; r < 4; ++r) {
                int row = row0 + rh * 64 + mt * 16 + qd * 4 + r;
                out[(size_t)row * 256 + col] = acc[mt][nt][r] + bv;
            }
        }
}

extern "C" void kernel_launch(void* const* d_in, const int* in_sizes, int n_in,
                              void* d_out, int out_size, void* d_ws, size_t ws_size,
                              hipStream_t stream) {
    const float* x      = (const float*)d_in[0];
    const float* Wqk    = (const float*)d_in[1];
    const float* Wv     = (const float*)d_in[2];
    const float* Wpos   = (const float*)d_in[3];
    const float* bpos   = (const float*)d_in[4];
    const float* Wproj  = (const float*)d_in[5];
    const float* bproj  = (const float*)d_in[6];
    const float* gating = (const float*)d_in[7];
    float* out = (float*)d_out;

    ushort* gpos     = (ushort*)d_ws;             // 8*304*304 = 739,328
    ushort* x_bf     = gpos + 739328;             // 4,915,200
    ushort* wqkv_bf  = x_bf + 4915200;            // 196,608 (Wqk 0..511, Wv 512..767)
    ushort* wproj_bf = wqkv_bf + 196608;          // 65,536
    ushort* q_bf     = wproj_bf + 65536;          // 4,915,200 each
    ushort* k_bf     = q_bf + 4915200;
    ushort* v_bf     = k_bf + 4915200;
    ushort* o_bf     = v_bf + 4915200;

    prep_kernel<<<5664, 256, 0, stream>>>(x, Wqk, Wv, Wproj, Wpos, bpos, gating,
                                          x_bf, wqkv_bf, wproj_bf, gpos);
    gemm_qkv_mfma<<<dim3(6, 150), 256, 0, stream>>>(x_bf, wqkv_bf, q_bf, k_bf, v_bf);
    attn_mfma<<<dim3(64 * HEADS), 256, 0, stream>>>(q_bf, k_bf, v_bf, gpos, gating, o_bf);
    gemm_proj_mfma<<<dim3(2, 150), 256, 0, stream>>>(o_bf, wproj_bf, bproj, out);
}